// Round 18
// baseline (339.070 us; speedup 1.0000x reference)
//
#include <hip/hip_runtime.h>
#include <math.h>

// FNO2d: B=8, H=W=128, WIDTH=32, MODES=12, NL=6
// All GEMM-shaped work on MFMA. y carried as bf16 hi/lo [pix][32].
// F1 carried as bf16 hi/lo [bc][col24][h128] -> dfth B-frags direct from L2.
// layer = {dfth(MFMA, no LDS), mixid(mix + MFMA iDFT), combine3(MFMA x3)}.
// Head fc1..fc5 fused MFMA, fc1/fc3 interleaved halves (20KB LDS, 8 blk/CU).

#define NL 6

typedef unsigned short u16;
typedef __attribute__((ext_vector_type(8))) short short8v;
typedef __attribute__((ext_vector_type(8))) unsigned short ushort8v;
typedef __attribute__((ext_vector_type(4))) unsigned short ushort4v;
typedef __attribute__((ext_vector_type(4))) float f32x4;

// A&S 7.1.26 erf, branchless, raw v_rcp (max abs err ~1.5e-7)
__device__ __forceinline__ float gelu_f(float x){
  float z  = x*0.70710678118654752f;
  float az = fabsf(z);
  float t  = __builtin_amdgcn_rcpf(fmaf(0.3275911f, az, 1.0f));
  float p  = t*(0.254829592f + t*(-0.284496736f + t*(1.421413741f +
             t*(-1.453152027f + t*1.061405429f))));
  float e  = __expf(-z*z);
  float er = copysignf(fmaf(-p, e, 1.0f), z);
  return 0.5f*x*(1.0f + er);
}
__device__ __forceinline__ u16 f2bf(float x){
  unsigned u = __float_as_uint(x);
  u += 0x7FFF + ((u>>16)&1);
  return (u16)(u>>16);
}
__device__ __forceinline__ float bf2f(u16 h){
  return __uint_as_float(((unsigned)h)<<16);
}
// truncation split: hi = top16(v), lo = bf16_trunc(v - hi). Error class 2^-17.
__device__ __forceinline__ void split2(float v, u16 &hh, u16 &ll){
  unsigned u = __float_as_uint(v);
  hh = (u16)(u>>16);
  float lo = v - __uint_as_float(u & 0xFFFF0000u);
  ll = (u16)(__float_as_uint(lo)>>16);
}

// ---- fc0 + fused W-DFT: x -> Yb hi/lo [pix][32]; F1 hi/lo [bc][col][h] -----
__global__ __launch_bounds__(256) void k_fc0f(const float* __restrict__ x,
                      const float* __restrict__ W, const float* __restrict__ b,
                      u16* __restrict__ Ybh, u16* __restrict__ Ybl,
                      u16* __restrict__ F1h, u16* __restrict__ F1l){
  __shared__ float Ws[128];
  __shared__ float bs[32];
  __shared__ float ys2[2][32][132];
  int t = threadIdx.x;
  if (t < 128) Ws[t] = W[t];
  if (t < 32)  bs[t] = b[t];
  __syncthreads();
  int pix = blockIdx.x*256 + t;
  float4 xv = *reinterpret_cast<const float4*>(x + (size_t)pix*4);
  int r = t>>7, w = t&127;
  ushort8v hv[4], lv[4];
  #pragma unroll
  for (int c=0;c<32;c++){
    float acc = bs[c] + xv.x*Ws[c] + xv.y*Ws[32+c] + xv.z*Ws[64+c] + xv.w*Ws[96+c];
    ys2[r][c][w] = acc;
    u16 hh, ll; split2(acc, hh, ll);
    hv[c>>3][c&7] = hh; lv[c>>3][c&7] = ll;
  }
  {
    u16* dh = Ybh + (size_t)pix*32;
    u16* dl = Ybl + (size_t)pix*32;
    #pragma unroll
    for (int q=0;q<4;q++){
      *reinterpret_cast<ushort8v*>(dh + q*8) = hv[q];
      *reinterpret_cast<ushort8v*>(dl + q*8) = lv[q];
    }
  }
  __syncthreads();
  int c2 = t>>3, wq = t&7;
  float stc[12], sts[12];
  #pragma unroll
  for (int k=0;k<12;k++){ float s,c; sincospif(k*(1.0f/64.0f), &s, &c); stc[k]=c; sts[k]=s; }
  int gr0 = blockIdx.x*2;
  #pragma unroll
  for (int r2=0;r2<2;r2++){
    float cr[12], ci[12], aR[12], aI[12];
    #pragma unroll
    for (int k=0;k<12;k++){
      float s,c; sincospif((float)(k*wq)*0.25f, &s, &c);
      cr[k]=c; ci[k]=s; aR[k]=0.f; aI[k]=0.f;
    }
    const float* rowp = &ys2[r2][c2][wq*16];
    #pragma unroll
    for (int q=0;q<4;q++){
      float4 xq = *reinterpret_cast<const float4*>(rowp + q*4);
      float xa[4]={xq.x,xq.y,xq.z,xq.w};
      #pragma unroll
      for (int e=0;e<4;e++){
        float xw = xa[e];
        #pragma unroll
        for (int k=0;k<12;k++){
          aR[k] += xw*cr[k];
          aI[k] -= xw*ci[k];
          float nc = cr[k]*stc[k] - ci[k]*sts[k];
          ci[k]    = cr[k]*sts[k] + ci[k]*stc[k];
          cr[k] = nc;
        }
      }
    }
    #pragma unroll
    for (int k=0;k<12;k++){
      aR[k] += __shfl_xor(aR[k],1); aR[k] += __shfl_xor(aR[k],2); aR[k] += __shfl_xor(aR[k],4);
      aI[k] += __shfl_xor(aI[k],1); aI[k] += __shfl_xor(aI[k],2); aI[k] += __shfl_xor(aI[k],4);
    }
    if (wq==0){
      int g = gr0 + r2; int b2 = g>>7, h2 = g&127;
      size_t base = (size_t)(b2*32+c2)*3072 + h2;
      #pragma unroll
      for (int k=0;k<12;k++){
        u16 hh, ll;
        split2(aR[k], hh, ll);
        F1h[base + (2*k)*128]   = hh; F1l[base + (2*k)*128]   = ll;
        split2(aI[k], hh, ll);
        F1h[base + (2*k+1)*128] = hh; F1l[base + (2*k+1)*128] = ll;
      }
    }
  }
}

// ------- one-time weight transpose -> wT[l][hf][kym][kx][o][i][ri] ---------
__global__ __launch_bounds__(256) void k_wtrans(const float* __restrict__ w, float* __restrict__ wT){
  __shared__ float buf[16][32][25];
  int t=threadIdx.x;
  int beta = blockIdx.x;            // 288
  int l = beta/48, r = beta%48;
  int hf = r/24; int r2 = r%24;
  int kym = r2>>1; int i0 = (r2&1)*16;
  const float* src = w + (size_t)l*589824 + (size_t)hf*294912 + kym*24;
  float* dst = wT + (size_t)l*589824 + (size_t)hf*294912 + (size_t)kym*24576;
  for (int j=t; j<12288; j+=256){
    int i = j/768, rem = j%768, o = rem/24, kxri = rem%24;
    buf[i][o][kxri] = src[(size_t)(i0+i)*9216 + o*288 + kxri];
  }
  __syncthreads();
  for (int j=t; j<12288; j+=256){
    int kx = j>>10, rem = j&1023, i = rem>>6, orr = rem&63, o = orr>>1, ri = orr&1;
    dst[(size_t)kx*2048 + o*64 + (i0+i)*2 + ri] = buf[i][o][kx*2+ri];
  }
}

// ------- head weight prep + twiddle matrices + conv weights -----------------
__global__ __launch_bounds__(256) void k_wprep(const float* __restrict__ W1, const float* __restrict__ W3,
                       const float* __restrict__ W4,
                       const float* __restrict__ b4, const float* __restrict__ w5,
                       const float* __restrict__ b5,
                       const float* __restrict__ wW, const float* __restrict__ wb,
                       const float* __restrict__ bb, const float* __restrict__ cb,
                       u16* __restrict__ W1h, u16* __restrict__ W1l,
                       u16* __restrict__ W3h, u16* __restrict__ W3l,
                       u16* __restrict__ W4h, u16* __restrict__ W4l,
                       u16* __restrict__ Emh, u16* __restrict__ Eml,
                       u16* __restrict__ E2h, u16* __restrict__ E2l,
                       u16* __restrict__ E3h, u16* __restrict__ E3l,
                       u16* __restrict__ Wch, u16* __restrict__ Wcl,
                       u16* __restrict__ E4h, u16* __restrict__ E4l,
                       float* __restrict__ bsum, float* __restrict__ c45){
  __shared__ float buf[32][132];
  int t = threadIdx.x, bid = blockIdx.x;   // 18 blocks
  if (bid < 8){
    int k0 = bid*32;
    for (int i=t;i<4096;i+=256){ int k=i>>7, n=i&127; buf[k][n] = W3[(size_t)(k0+k)*128 + n]; }
    __syncthreads();
    int n = t>>1, kq = t&1;
    #pragma unroll
    for (int kk=0;kk<16;kk++){
      int k = kq*16 + kk;
      float v = buf[k][n];
      u16 hh = f2bf(v);
      W3h[(size_t)bid*4096 + n*32 + k] = hh;
      W3l[(size_t)bid*4096 + n*32 + k] = f2bf(v - bf2f(hh));
    }
  } else if (bid == 8){
    __shared__ float red[256];
    int n = t;
    #pragma unroll
    for (int c=0;c<32;c++){
      float v = W1[(size_t)c*256 + n];
      u16 hh = f2bf(v);
      W1h[n*32 + c] = hh;
      W1l[n*32 + c] = f2bf(v - bf2f(hh));
    }
    red[t] = (t<128)? b4[t]*w5[t] : 0.f;
    __syncthreads();
    for (int s2=128; s2>0; s2>>=1){
      if (t<s2) red[t] += red[t+s2];
      __syncthreads();
    }
    if (t==0) c45[0] = red[0] + b5[0];
  } else if (bid <= 12){
    int k0 = (bid-9)*32;
    for (int i=t;i<4096;i+=256){ int k=i>>7, n=i&127; buf[k][n] = W4[(size_t)(k0+k)*128 + n]; }
    __syncthreads();
    int n = t>>1, kq = t&1;
    #pragma unroll
    for (int kk=0;kk<16;kk++){
      int k = kq*16 + kk;
      float v = buf[k][n];
      u16 hh = f2bf(v);
      W4h[(size_t)(bid-9)*4096 + n*32 + k] = hh;
      W4l[(size_t)(bid-9)*4096 + n*32 + k] = f2bf(v - bf2f(hh));
    }
  } else if (bid == 13){
    for (int i=t;i<4096;i+=256){
      int m=i>>7, w=i&127;
      float v=0.f;
      if (m<24){ float s,c; sincospif((float)((m>>1)*w)*(1.0f/64.0f), &s, &c); v = (m&1)? -s : c; }
      u16 hh, ll; split2(v, hh, ll);
      Emh[i]=hh; Eml[i]=ll;
    }
  } else if (bid == 14){
    for (int i=t;i<12288;i+=256){
      int m=i>>8, k=i&255;
      int kyi = (m<24)? m : m-24;
      int ky  = (kyi<12)? kyi : kyi+104;
      int h   = k&127;
      int mm  = (ky*h)&127;
      float s,c; sincospif((float)mm*(1.0f/64.0f), &s, &c);
      bool sinSlot = k>=128;
      float v;
      if (m<24) v = sinSlot? s : c;
      else      v = sinSlot? c : -s;
      u16 hh, ll; split2(v, hh, ll);
      E2h[i]=hh; E2l[i]=ll;
    }
  } else if (bid == 15){
    for (int i=t;i<8192;i+=256){
      int h=i>>6, k=i&63;
      float v=0.f;
      if (k<48){
        int kyi = (k<24)? k : k-24;
        int ky  = (kyi<12)? kyi : kyi+104;
        int mm  = (ky*h)&127;
        float s,c; sincospif((float)mm*(1.0f/64.0f), &s, &c);
        v = ((k<24)? c : s) * (1.0f/16384.0f);
      }
      u16 hh, ll; split2(v, hh, ll);
      E3h[i]=hh; E3l[i]=ll;
    }
  } else if (bid == 16){
    for (int i=t;i<6144;i+=256){
      float v = wW[i];
      u16 hh, ll; split2(v, hh, ll);
      Wch[i]=hh; Wcl[i]=ll;
    }
    if (t < 192) bsum[t] = wb[t] + bb[t] + cb[t];
  } else {
    for (int i=t;i<4096;i+=256){
      int w=i>>5, k=i&31;
      float v=0.f;
      if (k < 24){
        int kx = k>>1, ri = k&1;
        if (kx==0) v = ri? 0.f : 1.f;
        else {
          float s,c; sincospif((float)(kx*w)*(1.0f/64.0f), &s, &c);
          v = ri? -2.f*s : 2.f*c;
        }
      }
      u16 hh, ll; split2(v, hh, ll);
      E4h[i]=hh; E4l[i]=ll;
    }
  }
}

// ------- H-DFT via MFMA, no LDS: B-frags direct from F1 hi/lo ---------------
__global__ __launch_bounds__(256) void k_dfth(const u16* __restrict__ F1h, const u16* __restrict__ F1l,
                      const u16* __restrict__ E2h, const u16* __restrict__ E2l,
                      float* __restrict__ F2){
  int t=threadIdx.x;
  int bc = blockIdx.x;                            // 256 blocks
  int b = bc>>5, c = bc&31;
  int wv = t>>6, lane = t&63, lr = lane&15, lg = lane>>4;
  if (wv < 3){
    const u16* bh = F1h + (size_t)bc*3072;
    const u16* bl = F1l + (size_t)bc*3072;
    f32x4 acc = (f32x4){0.f,0.f,0.f,0.f};
    #pragma unroll
    for (int ks=0; ks<8; ++ks){
      short8v af = *reinterpret_cast<const short8v*>(E2h + (size_t)(wv*16+lr)*256 + ks*32 + lg*8);
      short8v ag = *reinterpret_cast<const short8v*>(E2l + (size_t)(wv*16+lr)*256 + ks*32 + lg*8);
      short8v bf = *reinterpret_cast<const short8v*>(bh + lr*256 + ks*32 + lg*8);
      short8v bg = *reinterpret_cast<const short8v*>(bl + lr*256 + ks*32 + lg*8);
      acc = __builtin_amdgcn_mfma_f32_16x16x32_bf16(af, bf, acc, 0,0,0);
      acc = __builtin_amdgcn_mfma_f32_16x16x32_bf16(af, bg, acc, 0,0,0);
      acc = __builtin_amdgcn_mfma_f32_16x16x32_bf16(ag, bf, acc, 0,0,0);
    }
    if (lr < 12){
      #pragma unroll
      for (int r=0;r<4;r++){
        int m = wv*16 + 4*lg + r;
        int kyi = (m<24)? m : m-24;
        int ri  = (m<24)? 0 : 1;
        F2[(((size_t)b*24 + kyi)*24 + 2*lr + ri)*32 + c] = acc[r];
      }
    }
  }
}

// ------- fused mode-mix + MFMA inverse H-DFT: F2 x wT2 -> S1 hi/lo ----------
__global__ __launch_bounds__(576) void k_mixid(const float* __restrict__ F2, const float* __restrict__ wTl,
                      const u16* __restrict__ E3h, const u16* __restrict__ E3l,
                      u16* __restrict__ S1h, u16* __restrict__ S1l){
  __shared__ u16 Bh[32*72], Bl[32*72];
  int t=threadIdx.x;
  int bo = blockIdx.x;            // 256 = b*32+o
  int b = bo>>5, o = bo&31;
  for (int i=t; i<24*24; i+=576){
    int row = i/24, k = 48 + i - (i/24)*24;
    Bh[row*72 + k] = 0; Bl[row*72 + k] = 0;
  }
  {
    int pair = t>>1, half = t&1;  // pair < 288
    int kx = pair%12, kyi = pair/12;
    int hf = kyi<12?0:1, kym = kyi<12?kyi:kyi-12;
    const float* fpr = F2 + (((size_t)b*24 + kyi)*24 + 2*kx)*32 + half*16;
    const float* fpi = fpr + 32;
    const float* wp = wTl + (size_t)(hf*12+kym)*24576 + kx*2048 + o*64 + half*32;
    float gr=0.f, gi=0.f;
    #pragma unroll 8
    for (int i=0;i<16;i++){
      float2 wv = *reinterpret_cast<const float2*>(wp + 2*i);
      float ar = fpr[i], ai = fpi[i];
      gr += ar*wv.x - ai*wv.y;
      gi += ar*wv.y + ai*wv.x;
    }
    gr += __shfl_xor(gr,1);
    gi += __shfl_xor(gi,1);
    if (half==0){
      u16 grh, grl, gih, gil, nih, nil;
      split2(gr, grh, grl);
      split2(gi, gih, gil);
      split2(-gi, nih, nil);
      int r0 = (2*kx)*72, r1 = (2*kx+1)*72;
      Bh[r0 + kyi]      = grh; Bl[r0 + kyi]      = grl;
      Bh[r0 + 24 + kyi] = nih; Bl[r0 + 24 + kyi] = nil;
      Bh[r1 + kyi]      = gih; Bl[r1 + kyi]      = gil;
      Bh[r1 + 24 + kyi] = grh; Bl[r1 + 24 + kyi] = grl;
    }
  }
  __syncthreads();
  int wv = t>>6, lane = t&63, lr = lane&15, lg = lane>>4;
  if (wv < 8){
    f32x4 acc[2];
    acc[0] = (f32x4){0.f,0.f,0.f,0.f};
    acc[1] = (f32x4){0.f,0.f,0.f,0.f};
    #pragma unroll
    for (int ks=0; ks<2; ++ks){
      short8v af = *reinterpret_cast<const short8v*>(E3h + (size_t)(wv*16+lr)*64 + ks*32 + lg*8);
      short8v ag = *reinterpret_cast<const short8v*>(E3l + (size_t)(wv*16+lr)*64 + ks*32 + lg*8);
      #pragma unroll
      for (int nt=0; nt<2; ++nt){
        short8v bf = *reinterpret_cast<const short8v*>(&Bh[(nt*16+lr)*72 + ks*32 + lg*8]);
        short8v bg = *reinterpret_cast<const short8v*>(&Bl[(nt*16+lr)*72 + ks*32 + lg*8]);
        acc[nt] = __builtin_amdgcn_mfma_f32_16x16x32_bf16(af, bf, acc[nt], 0,0,0);
        acc[nt] = __builtin_amdgcn_mfma_f32_16x16x32_bf16(af, bg, acc[nt], 0,0,0);
        acc[nt] = __builtin_amdgcn_mfma_f32_16x16x32_bf16(ag, bf, acc[nt], 0,0,0);
      }
    }
    #pragma unroll
    for (int nt=0; nt<2; ++nt){
      int n = nt*16 + lr;
      if (n < 24){
        #pragma unroll
        for (int r=0;r<4;r++){
          int h = wv*16 + 4*lg + r;
          size_t off = (size_t)bo*3072 + h*24 + n;
          u16 hh, ll; split2(acc[nt][r], hh, ll);
          S1h[off] = hh; S1l[off] = ll;
        }
      }
    }
  }
}

// --------- combine3 (256 threads): conv1x1 + spec iW-DFT via MFMA + bias
//           + GELU -> Yb hi/lo out; non-LAST also MFMA W-DFT -> F1 hi/lo.
template<int LAST>
__global__ __launch_bounds__(256) void k_combine3(
    const u16* __restrict__ Ybh_in, const u16* __restrict__ Ybl_in,
    const u16* __restrict__ S1h, const u16* __restrict__ S1l,
    const float* __restrict__ x,
    const u16* __restrict__ Wch, const u16* __restrict__ Wcl,   // + l*1024
    const u16* __restrict__ E4h, const u16* __restrict__ E4l,
    const float* __restrict__ bsuml,                            // + l*32
    const float* __restrict__ bWl, const float* __restrict__ cWl,
    const u16* __restrict__ Emh, const u16* __restrict__ Eml,
    u16* __restrict__ F1h, u16* __restrict__ F1l,
    u16* __restrict__ Ybh_out, u16* __restrict__ Ybl_out){
  __shared__ u16 ybsp[2][32][136];
  __shared__ float bs[32], bwS[64], cwS[96];
  int t=threadIdx.x;
  int b = blockIdx.x>>7, h = blockIdx.x&127;
  if (t<32) bs[t]=bsuml[t];
  else if (t>=64 && t<128) bwS[t-64]=bWl[t-64];
  else if (t>=128 && t<224) cwS[t-128]=cWl[t-128];
  __syncthreads();
  int wv=t>>6, lane=t&63, lr=lane&15, lg=lane>>4;
  f32x4 acc[2][2];
  #pragma unroll
  for (int ot=0;ot<2;++ot){ acc[ot][0]=(f32x4){0,0,0,0}; acc[ot][1]=(f32x4){0,0,0,0}; }
  // conv1x1: A=Wc[o][c] hi/lo, B=y[w][c] hi/lo (direct from global)
  #pragma unroll
  for (int ot=0; ot<2; ++ot){
    int o = ot*16+lr;
    short8v af = *reinterpret_cast<const short8v*>(Wch + o*32 + lg*8);
    short8v al = *reinterpret_cast<const short8v*>(Wcl + o*32 + lg*8);
    #pragma unroll
    for (int j=0;j<2;++j){
      int w = (2*wv+j)*16 + lr;
      size_t yoff = (((size_t)(b*128+h))*128 + w)*32 + lg*8;
      short8v bh = *reinterpret_cast<const short8v*>(Ybh_in + yoff);
      short8v bl = *reinterpret_cast<const short8v*>(Ybl_in + yoff);
      acc[ot][j] = __builtin_amdgcn_mfma_f32_16x16x32_bf16(af, bh, acc[ot][j], 0,0,0);
      acc[ot][j] = __builtin_amdgcn_mfma_f32_16x16x32_bf16(af, bl, acc[ot][j], 0,0,0);
      acc[ot][j] = __builtin_amdgcn_mfma_f32_16x16x32_bf16(al, bh, acc[ot][j], 0,0,0);
    }
  }
  // spec: A=S1[o][k<24 pad32] hi/lo, B=E4[w][k] hi/lo
  #pragma unroll
  for (int ot=0; ot<2; ++ot){
    int o = ot*16+lr;
    size_t soff = (((size_t)(b*32+o))*128 + h)*24 + lg*8;
    short8v ah = *reinterpret_cast<const short8v*>(S1h + soff);
    short8v al2 = *reinterpret_cast<const short8v*>(S1l + soff);
    #pragma unroll
    for (int j=0;j<2;++j){
      int w = (2*wv+j)*16 + lr;
      short8v eh = *reinterpret_cast<const short8v*>(E4h + w*32 + lg*8);
      short8v el = *reinterpret_cast<const short8v*>(E4l + w*32 + lg*8);
      acc[ot][j] = __builtin_amdgcn_mfma_f32_16x16x32_bf16(ah, eh, acc[ot][j], 0,0,0);
      acc[ot][j] = __builtin_amdgcn_mfma_f32_16x16x32_bf16(al2, eh, acc[ot][j], 0,0,0);
      acc[ot][j] = __builtin_amdgcn_mfma_f32_16x16x32_bf16(ah, el, acc[ot][j], 0,0,0);
    }
  }
  // bias + gelu + emit (D: row o = ot*16+4lg+r, col w = (2wv+j)*16+lr)
  float gx = h*(1.0f/127.0f);
  #pragma unroll
  for (int j=0;j<2;++j){
    int w = (2*wv+j)*16 + lr;
    float4 xm = *reinterpret_cast<const float4*>(x + (((size_t)(b*128+h))*128+w)*4);
    float gy = w*(1.0f/127.0f);
    #pragma unroll
    for (int ot=0;ot<2;++ot){
      ushort4v hv, lvv;
      #pragma unroll
      for (int r=0;r<4;++r){
        int o = ot*16 + 4*lg + r;
        float v = acc[ot][j][r] + bs[o] + gx*bwS[2*o] + gy*bwS[2*o+1]
                + xm.y*cwS[3*o] + xm.z*cwS[3*o+1] + xm.w*cwS[3*o+2];
        float g = gelu_f(v);
        u16 hh, ll; split2(g, hh, ll);
        hv[r]=hh; lvv[r]=ll;
        if constexpr(!LAST){ ybsp[0][o][w]=hh; ybsp[1][o][w]=ll; }
      }
      size_t base = (((size_t)(b*128+h))*128 + w)*32 + ot*16 + 4*lg;
      *reinterpret_cast<ushort4v*>(Ybh_out + base) = hv;
      *reinterpret_cast<ushort4v*>(Ybl_out + base) = lvv;
    }
  }
  if constexpr(!LAST){
    __syncthreads();
    // forward W-DFT via MFMA: F1[o][m] = sum_w y[o][w]*Em[m][w] (bf16x3)
    int mt = wv&1, oj = wv>>1;
    f32x4 accm = (f32x4){0.f,0.f,0.f,0.f};
    #pragma unroll
    for (int ks=0; ks<4; ++ks){
      short8v ef = *reinterpret_cast<const short8v*>(Emh + (size_t)(mt*16+lr)*128 + ks*32 + lg*8);
      short8v eg = *reinterpret_cast<const short8v*>(Eml + (size_t)(mt*16+lr)*128 + ks*32 + lg*8);
      short8v yf = *reinterpret_cast<const short8v*>(&ybsp[0][oj*16+lr][ks*32+lg*8]);
      short8v yg = *reinterpret_cast<const short8v*>(&ybsp[1][oj*16+lr][ks*32+lg*8]);
      accm = __builtin_amdgcn_mfma_f32_16x16x32_bf16(ef, yf, accm, 0,0,0);
      accm = __builtin_amdgcn_mfma_f32_16x16x32_bf16(ef, yg, accm, 0,0,0);
      accm = __builtin_amdgcn_mfma_f32_16x16x32_bf16(eg, yf, accm, 0,0,0);
    }
    if (mt==0 || lg<2){
      int m = mt*16 + 4*lg;
      int o = oj*16 + lr;
      size_t base = (size_t)(b*32+o)*3072 + h;
      #pragma unroll
      for (int r=0;r<4;++r){
        u16 hh, ll; split2(accm[r], hh, ll);
        F1h[base + (m+r)*128] = hh;
        F1l[base + (m+r)*128] = ll;
      }
    }
  }
}

// ---- fused head: fc1/fc3 interleaved halves (LDS 20KB), fc4, fc5 -----------
__global__ __launch_bounds__(256) void k_headm(
    const u16* __restrict__ Yb,                                 // [pix][32] bf16 hi
    const u16* __restrict__ W1h, const u16* __restrict__ W1l,
    const float* __restrict__ b1,
    const u16* __restrict__ W3h, const u16* __restrict__ W3l,
    const float* __restrict__ b3,
    const u16* __restrict__ W4h, const u16* __restrict__ W4l,
    const float* __restrict__ c45, const float* __restrict__ w5,
    float* __restrict__ out){
  __shared__ u16 Ac[64*136];   // 17408 B; A2 unions into it
  __shared__ float b1s[256];
  __shared__ float b3s[128], w5s[128];
  __shared__ float part2[2][64];
  int t = threadIdx.x;
  int wv = t>>6, lane = t&63, lr = lane&15, lg = lane>>4;
  int P0 = blockIdx.x*64;
  b1s[t] = b1[t];
  if (t<128){ b3s[t]=b3[t]; w5s[t]=w5[t]; }
  int wn3 = wv>>1, wp = wv&1;
  short8v yb;
  {
    size_t p = (size_t)P0 + wv*16 + lr;
    yb = *reinterpret_cast<const short8v*>(Yb + p*32 + lg*8);
  }
  f32x4 acc3[4][2];
  #pragma unroll
  for (int i=0;i<4;i++){ acc3[i][0]=(f32x4){0,0,0,0}; acc3[i][1]=(f32x4){0,0,0,0}; }
  __syncthreads();   // biases ready

  #pragma unroll
  for (int half=0; half<2; ++half){
    // fc1 for kt in [half*4, half*4+4): wave's 16 pixels
    unsigned q[4][2][2];
    #pragma unroll
    for (int kq=0; kq<4; ++kq){
      int kt = half*4 + kq;
      f32x4 a1[2];
      a1[0]=(f32x4){0,0,0,0}; a1[1]=(f32x4){0,0,0,0};
      #pragma unroll
      for (int i=0;i<2;i++){
        int n1 = kt*32 + i*16 + lr;
        short8v w1f = *reinterpret_cast<const short8v*>(W1h + (size_t)n1*32 + lg*8);
        short8v w1g = *reinterpret_cast<const short8v*>(W1l + (size_t)n1*32 + lg*8);
        a1[i] = __builtin_amdgcn_mfma_f32_16x16x32_bf16(w1f, yb, a1[i], 0,0,0);
        a1[i] = __builtin_amdgcn_mfma_f32_16x16x32_bf16(w1g, yb, a1[i], 0,0,0);
      }
      #pragma unroll
      for (int i=0;i<2;i++){
        int n1b = kt*32 + i*16 + 4*lg;
        u16 v0 = f2bf(gelu_f(a1[i][0] + b1s[n1b+0]));
        u16 v1 = f2bf(gelu_f(a1[i][1] + b1s[n1b+1]));
        u16 v2 = f2bf(gelu_f(a1[i][2] + b1s[n1b+2]));
        u16 v3 = f2bf(gelu_f(a1[i][3] + b1s[n1b+3]));
        q[kq][i][0] = (unsigned)v0 | ((unsigned)v1<<16);
        q[kq][i][1] = (unsigned)v2 | ((unsigned)v3<<16);
      }
    }
    // dump this half (p rows, n1-local 0..127)
    {
      int p = wv*16 + lr;
      #pragma unroll
      for (int kq=0; kq<4; ++kq){
        #pragma unroll
        for (int i=0;i<2;i++){
          union { unsigned u[2]; ushort4v s; } cv;
          cv.u[0] = q[kq][i][0]; cv.u[1] = q[kq][i][1];
          *reinterpret_cast<ushort4v*>(&Ac[p*136 + kq*32 + i*16 + 4*lg]) = cv.s;
        }
      }
    }
    __syncthreads();
    // fc3 for this half
    #pragma unroll
    for (int kq=0; kq<4; ++kq){
      int kt = half*4 + kq;
      short8v ab[2];
      #pragma unroll
      for (int j=0;j<2;j++){
        int pb = wp*32 + j*16 + lr;
        ab[j] = *reinterpret_cast<const short8v*>(&Ac[pb*136 + kq*32 + lg*8]);
      }
      #pragma unroll
      for (int i=0;i<4;i++){
        int n3 = wn3*64 + i*16 + lr;
        short8v w3f = *reinterpret_cast<const short8v*>(W3h + (size_t)kt*4096 + n3*32 + lg*8);
        short8v w3g = *reinterpret_cast<const short8v*>(W3l + (size_t)kt*4096 + n3*32 + lg*8);
        #pragma unroll
        for (int j=0;j<2;j++){
          acc3[i][j] = __builtin_amdgcn_mfma_f32_16x16x32_bf16(w3f, ab[j], acc3[i][j], 0,0,0);
          acc3[i][j] = __builtin_amdgcn_mfma_f32_16x16x32_bf16(w3g, ab[j], acc3[i][j], 0,0,0);
        }
      }
    }
    __syncthreads();   // before next dump / stage-B overwrite
  }
  // stage B: gelu(fc3) -> A2 [64p][136] bf16 (RNE), unions into Ac
  u16* A2 = Ac;
  #pragma unroll
  for (int i=0;i<4;i++){
    int n3b = wn3*64 + i*16 + 4*lg;
    #pragma unroll
    for (int j=0;j<2;j++){
      int p = wp*32 + j*16 + lr;
      ushort4v hv;
      #pragma unroll
      for (int r=0;r<4;r++){
        hv[r] = f2bf(gelu_f(acc3[i][j][r] + b3s[n3b+r]));
      }
      *reinterpret_cast<ushort4v*>(&A2[p*136 + n3b]) = hv;
    }
  }
  __syncthreads();
  f32x4 acc4[4][2];
  #pragma unroll
  for (int i=0;i<4;i++){ acc4[i][0]=(f32x4){0,0,0,0}; acc4[i][1]=(f32x4){0,0,0,0}; }
  #pragma unroll
  for (int ks=0; ks<4; ++ks){
    short8v p2[2];
    #pragma unroll
    for (int j=0;j<2;j++){
      int p = wp*32 + j*16 + lr;
      p2[j] = *reinterpret_cast<const short8v*>(&A2[p*136 + ks*32 + lg*8]);
    }
    #pragma unroll
    for (int i2=0;i2<4;i2++){
      int n4 = wn3*64 + i2*16 + lr;
      short8v w4f = *reinterpret_cast<const short8v*>(W4h + (size_t)ks*4096 + n4*32 + lg*8);
      short8v w4g = *reinterpret_cast<const short8v*>(W4l + (size_t)ks*4096 + n4*32 + lg*8);
      #pragma unroll
      for (int j=0;j<2;j++){
        acc4[i2][j] = __builtin_amdgcn_mfma_f32_16x16x32_bf16(w4f, p2[j], acc4[i2][j], 0,0,0);
        acc4[i2][j] = __builtin_amdgcn_mfma_f32_16x16x32_bf16(w4g, p2[j], acc4[i2][j], 0,0,0);
      }
    }
  }
  #pragma unroll
  for (int j=0;j<2;j++){
    float part = 0.f;
    #pragma unroll
    for (int i2=0;i2<4;i2++){
      #pragma unroll
      for (int r=0;r<4;r++){
        int n4 = wn3*64 + i2*16 + 4*lg + r;
        part += acc4[i2][j][r] * w5s[n4];
      }
    }
    part += __shfl_xor(part, 16); part += __shfl_xor(part, 32);
    if (lg==0) part2[wn3][wp*32 + j*16 + lr] = part;
  }
  __syncthreads();
  if (t<64) out[P0 + t] = part2[0][t] + part2[1][t] + c45[0];
}

extern "C" void kernel_launch(void* const* d_in, const int* in_sizes, int n_in,
                              void* d_out, int out_size, void* d_ws, size_t ws_size,
                              hipStream_t stream){
  const float* x     = (const float*)d_in[0];
  const float* fc0_W = (const float*)d_in[1];
  const float* fc0_b = (const float*)d_in[2];
  const float* spec_w= (const float*)d_in[3];
  const float* wW    = (const float*)d_in[4];
  const float* wb    = (const float*)d_in[5];
  const float* bW    = (const float*)d_in[6];
  const float* bb    = (const float*)d_in[7];
  const float* cW    = (const float*)d_in[8];
  const float* cb    = (const float*)d_in[9];
  const float* fc1_W = (const float*)d_in[10];
  const float* fc1_b = (const float*)d_in[11];
  const float* fc3_W = (const float*)d_in[12];
  const float* fc3_b = (const float*)d_in[13];
  const float* fc4_W = (const float*)d_in[14];
  const float* fc4_b = (const float*)d_in[15];
  const float* fc5_W = (const float*)d_in[16];
  const float* fc5_b = (const float*)d_in[17];
  float* out = (float*)d_out;
  float* ws  = (float*)d_ws;

  // workspace map
  u16*   YbA  = (u16*)ws;                  // 8,388,608 u16
  u16*   YbB  = YbA + 8388608;             // 8,388,608 u16
  float* wT   = ws + 8388608;              // 3,538,944 f
  float* F2   = wT + 3538944;              //   147,456 f
  u16*   S1h  = (u16*)(F2 + 147456);       //   786,496 u16
  u16*   S1l  = S1h + 786496;              //   786,496 u16
  u16*   F1h  = S1l + 786496;              //   787,456 u16 (1024 pad)
  u16*   F1l  = F1h + 787456;              //   787,456 u16
  float* WP   = (float*)(F1l + 787456);
  u16*   W1h = (u16*)WP;
  u16*   W1l = W1h + 8192;
  u16*   W3h = W1l + 8192;
  u16*   W3l = W3h + 32768;
  u16*   W4h = W3l + 32768;
  u16*   W4l = W4h + 16384;
  u16*   Emh = W4l + 16384;
  u16*   Eml = Emh + 4096;
  u16*   E2h = Eml + 4096;
  u16*   E2l = E2h + 12288;
  u16*   E3h = E2l + 12288;
  u16*   E3l = E3h + 8192;
  u16*   Wch = E3l + 8192;
  u16*   Wcl = Wch + 6144;
  u16*   E4h = Wcl + 6144;
  u16*   E4l = E4h + 4096;
  float* bsum = (float*)(E4l + 4096);
  float* c45  = bsum + 192;
  u16*   YbhA = YbA;
  u16*   YblA = YbA + 4194304;
  u16*   YbhB = YbB;
  u16*   YblB = YbB + 4194304;

  k_fc0f<<<512,256,0,stream>>>(x, fc0_W, fc0_b, YbhA, YblA, F1h, F1l);
  k_wtrans<<<288,256,0,stream>>>(spec_w, wT);
  k_wprep<<<18,256,0,stream>>>(fc1_W, fc3_W, fc4_W, fc4_b, fc5_W, fc5_b,
                               wW, wb, bb, cb,
                               W1h, W1l, W3h, W3l, W4h, W4l, Emh, Eml,
                               E2h, E2l, E3h, E3l, Wch, Wcl, E4h, E4l,
                               bsum, c45);

  for (int l=0;l<NL;l++){
    const u16* Yih = (l&1)? YbhB : YbhA;
    const u16* Yil = (l&1)? YblB : YblA;
    u16* Yoh = (l&1)? YbhA : YbhB;
    u16* Yol = (l&1)? YblA : YblB;
    k_dfth<<<256,256,0,stream>>>(F1h, F1l, E2h, E2l, F2);
    k_mixid<<<256,576,0,stream>>>(F2, wT + (size_t)l*589824, E3h, E3l, S1h, S1l);
    if (l < NL-1){
      k_combine3<0><<<1024,256,0,stream>>>(Yih, Yil, S1h, S1l, x,
                                     Wch + l*1024, Wcl + l*1024, E4h, E4l,
                                     bsum + l*32, bW + (size_t)l*64, cW + (size_t)l*96,
                                     Emh, Eml, F1h, F1l, Yoh, Yol);
    } else {
      k_combine3<1><<<1024,256,0,stream>>>(Yih, Yil, S1h, S1l, x,
                                     Wch + l*1024, Wcl + l*1024, E4h, E4l,
                                     bsum + l*32, bW + (size_t)l*64, cW + (size_t)l*96,
                                     Emh, Eml, nullptr, nullptr, Yoh, Yol);
    }
  }

  // NL=6 even: final combine (l=5) reads B, writes A -> head reads YbhA
  k_headm<<<2048,256,0,stream>>>(YbhA, W1h, W1l, fc1_b, W3h, W3l, fc3_b,
                                 W4h, W4l, c45, fc5_W, out);
}

// Round 19
// 314.635 us; speedup vs baseline: 1.0777x; 1.0777x over previous
//
#include <hip/hip_runtime.h>
#include <math.h>

// FNO2d: B=8, H=W=128, WIDTH=32, MODES=12, NL=6
// All GEMM-shaped work on MFMA. y carried as bf16 hi/lo [pix][32].
// layer = {dfth(MFMA), mixid(mix + MFMA iDFT, bf16 S1 out),
//          combine3(MFMA conv1x1 + MFMA spec-iWDFT + bias/gelu + MFMA W-DFT)}.
// Head fc1..fc5 fused MFMA (fc1 hoisted, single-barrier handoff).
// == Revert to R17 configuration (session best: 315 us). ==

#define NL 6

typedef unsigned short u16;
typedef __attribute__((ext_vector_type(8))) short short8v;
typedef __attribute__((ext_vector_type(8))) unsigned short ushort8v;
typedef __attribute__((ext_vector_type(4))) unsigned short ushort4v;
typedef __attribute__((ext_vector_type(4))) float f32x4;

// A&S 7.1.26 erf, branchless, raw v_rcp (max abs err ~1.5e-7)
__device__ __forceinline__ float gelu_f(float x){
  float z  = x*0.70710678118654752f;
  float az = fabsf(z);
  float t  = __builtin_amdgcn_rcpf(fmaf(0.3275911f, az, 1.0f));
  float p  = t*(0.254829592f + t*(-0.284496736f + t*(1.421413741f +
             t*(-1.453152027f + t*1.061405429f))));
  float e  = __expf(-z*z);
  float er = copysignf(fmaf(-p, e, 1.0f), z);
  return 0.5f*x*(1.0f + er);
}
__device__ __forceinline__ u16 f2bf(float x){
  unsigned u = __float_as_uint(x);
  u += 0x7FFF + ((u>>16)&1);
  return (u16)(u>>16);
}
__device__ __forceinline__ float bf2f(u16 h){
  return __uint_as_float(((unsigned)h)<<16);
}
// truncation split: hi = top16(v), lo = bf16_trunc(v - hi). Error class 2^-17.
__device__ __forceinline__ void split2(float v, u16 &hh, u16 &ll){
  unsigned u = __float_as_uint(v);
  hh = (u16)(u>>16);
  float lo = v - __uint_as_float(u & 0xFFFF0000u);
  ll = (u16)(__float_as_uint(lo)>>16);
}

// ---- fc0 + fused W-DFT: x -> Yb hi/lo [pix][32]; also F1[bc][h][24] --------
__global__ __launch_bounds__(256) void k_fc0f(const float* __restrict__ x,
                      const float* __restrict__ W, const float* __restrict__ b,
                      u16* __restrict__ Ybh, u16* __restrict__ Ybl,
                      float* __restrict__ F1){
  __shared__ float Ws[128];
  __shared__ float bs[32];
  __shared__ float ys2[2][32][132];
  int t = threadIdx.x;
  if (t < 128) Ws[t] = W[t];
  if (t < 32)  bs[t] = b[t];
  __syncthreads();
  int pix = blockIdx.x*256 + t;
  float4 xv = *reinterpret_cast<const float4*>(x + (size_t)pix*4);
  int r = t>>7, w = t&127;
  ushort8v hv[4], lv[4];
  #pragma unroll
  for (int c=0;c<32;c++){
    float acc = bs[c] + xv.x*Ws[c] + xv.y*Ws[32+c] + xv.z*Ws[64+c] + xv.w*Ws[96+c];
    ys2[r][c][w] = acc;
    u16 hh, ll; split2(acc, hh, ll);
    hv[c>>3][c&7] = hh; lv[c>>3][c&7] = ll;
  }
  {
    u16* dh = Ybh + (size_t)pix*32;
    u16* dl = Ybl + (size_t)pix*32;
    #pragma unroll
    for (int q=0;q<4;q++){
      *reinterpret_cast<ushort8v*>(dh + q*8) = hv[q];
      *reinterpret_cast<ushort8v*>(dl + q*8) = lv[q];
    }
  }
  __syncthreads();
  int c2 = t>>3, wq = t&7;
  float stc[12], sts[12];
  #pragma unroll
  for (int k=0;k<12;k++){ float s,c; sincospif(k*(1.0f/64.0f), &s, &c); stc[k]=c; sts[k]=s; }
  int gr0 = blockIdx.x*2;
  #pragma unroll
  for (int r2=0;r2<2;r2++){
    float cr[12], ci[12], aR[12], aI[12];
    #pragma unroll
    for (int k=0;k<12;k++){
      float s,c; sincospif((float)(k*wq)*0.25f, &s, &c);
      cr[k]=c; ci[k]=s; aR[k]=0.f; aI[k]=0.f;
    }
    const float* rowp = &ys2[r2][c2][wq*16];
    #pragma unroll
    for (int q=0;q<4;q++){
      float4 xq = *reinterpret_cast<const float4*>(rowp + q*4);
      float xa[4]={xq.x,xq.y,xq.z,xq.w};
      #pragma unroll
      for (int e=0;e<4;e++){
        float xw = xa[e];
        #pragma unroll
        for (int k=0;k<12;k++){
          aR[k] += xw*cr[k];
          aI[k] -= xw*ci[k];
          float nc = cr[k]*stc[k] - ci[k]*sts[k];
          ci[k]    = cr[k]*sts[k] + ci[k]*stc[k];
          cr[k] = nc;
        }
      }
    }
    #pragma unroll
    for (int k=0;k<12;k++){
      aR[k] += __shfl_xor(aR[k],1); aR[k] += __shfl_xor(aR[k],2); aR[k] += __shfl_xor(aR[k],4);
      aI[k] += __shfl_xor(aI[k],1); aI[k] += __shfl_xor(aI[k],2); aI[k] += __shfl_xor(aI[k],4);
    }
    if (wq==0){
      int g = gr0 + r2; int b2 = g>>7, h2 = g&127;
      float* dst = F1 + ((size_t)(b2*32+c2)*128 + h2)*24;
      #pragma unroll
      for (int k=0;k<12;k++){ dst[2*k] = aR[k]; dst[2*k+1] = aI[k]; }
    }
  }
}

// ------- one-time weight transpose -> wT[l][hf][kym][kx][o][i][ri] ---------
__global__ __launch_bounds__(256) void k_wtrans(const float* __restrict__ w, float* __restrict__ wT){
  __shared__ float buf[16][32][25];
  int t=threadIdx.x;
  int beta = blockIdx.x;            // 288
  int l = beta/48, r = beta%48;
  int hf = r/24; int r2 = r%24;
  int kym = r2>>1; int i0 = (r2&1)*16;
  const float* src = w + (size_t)l*589824 + (size_t)hf*294912 + kym*24;
  float* dst = wT + (size_t)l*589824 + (size_t)hf*294912 + (size_t)kym*24576;
  for (int j=t; j<12288; j+=256){
    int i = j/768, rem = j%768, o = rem/24, kxri = rem%24;
    buf[i][o][kxri] = src[(size_t)(i0+i)*9216 + o*288 + kxri];
  }
  __syncthreads();
  for (int j=t; j<12288; j+=256){
    int kx = j>>10, rem = j&1023, i = rem>>6, orr = rem&63, o = orr>>1, ri = orr&1;
    dst[(size_t)kx*2048 + o*64 + (i0+i)*2 + ri] = buf[i][o][kx*2+ri];
  }
}

// ------- head weight prep + twiddle matrices + conv weights -----------------
__global__ __launch_bounds__(256) void k_wprep(const float* __restrict__ W1, const float* __restrict__ W3,
                       const float* __restrict__ W4,
                       const float* __restrict__ b4, const float* __restrict__ w5,
                       const float* __restrict__ b5,
                       const float* __restrict__ wW, const float* __restrict__ wb,
                       const float* __restrict__ bb, const float* __restrict__ cb,
                       u16* __restrict__ W1h, u16* __restrict__ W1l,
                       u16* __restrict__ W3h, u16* __restrict__ W3l,
                       u16* __restrict__ W4h, u16* __restrict__ W4l,
                       u16* __restrict__ Emh, u16* __restrict__ Eml,
                       u16* __restrict__ E2h, u16* __restrict__ E2l,
                       u16* __restrict__ E3h, u16* __restrict__ E3l,
                       u16* __restrict__ Wch, u16* __restrict__ Wcl,
                       u16* __restrict__ E4h, u16* __restrict__ E4l,
                       float* __restrict__ bsum, float* __restrict__ c45){
  __shared__ float buf[32][132];
  int t = threadIdx.x, bid = blockIdx.x;   // 18 blocks
  if (bid < 8){
    int k0 = bid*32;
    for (int i=t;i<4096;i+=256){ int k=i>>7, n=i&127; buf[k][n] = W3[(size_t)(k0+k)*128 + n]; }
    __syncthreads();
    int n = t>>1, kq = t&1;
    #pragma unroll
    for (int kk=0;kk<16;kk++){
      int k = kq*16 + kk;
      float v = buf[k][n];
      u16 hh = f2bf(v);
      W3h[(size_t)bid*4096 + n*32 + k] = hh;
      W3l[(size_t)bid*4096 + n*32 + k] = f2bf(v - bf2f(hh));
    }
  } else if (bid == 8){
    __shared__ float red[256];
    int n = t;
    #pragma unroll
    for (int c=0;c<32;c++){
      float v = W1[(size_t)c*256 + n];
      u16 hh = f2bf(v);
      W1h[n*32 + c] = hh;
      W1l[n*32 + c] = f2bf(v - bf2f(hh));
    }
    red[t] = (t<128)? b4[t]*w5[t] : 0.f;
    __syncthreads();
    for (int s2=128; s2>0; s2>>=1){
      if (t<s2) red[t] += red[t+s2];
      __syncthreads();
    }
    if (t==0) c45[0] = red[0] + b5[0];
  } else if (bid <= 12){
    int k0 = (bid-9)*32;
    for (int i=t;i<4096;i+=256){ int k=i>>7, n=i&127; buf[k][n] = W4[(size_t)(k0+k)*128 + n]; }
    __syncthreads();
    int n = t>>1, kq = t&1;
    #pragma unroll
    for (int kk=0;kk<16;kk++){
      int k = kq*16 + kk;
      float v = buf[k][n];
      u16 hh = f2bf(v);
      W4h[(size_t)(bid-9)*4096 + n*32 + k] = hh;
      W4l[(size_t)(bid-9)*4096 + n*32 + k] = f2bf(v - bf2f(hh));
    }
  } else if (bid == 13){
    for (int i=t;i<4096;i+=256){
      int m=i>>7, w=i&127;
      float v=0.f;
      if (m<24){ float s,c; sincospif((float)((m>>1)*w)*(1.0f/64.0f), &s, &c); v = (m&1)? -s : c; }
      u16 hh, ll; split2(v, hh, ll);
      Emh[i]=hh; Eml[i]=ll;
    }
  } else if (bid == 14){
    for (int i=t;i<12288;i+=256){
      int m=i>>8, k=i&255;
      int kyi = (m<24)? m : m-24;
      int ky  = (kyi<12)? kyi : kyi+104;
      int h   = k&127;
      int mm  = (ky*h)&127;
      float s,c; sincospif((float)mm*(1.0f/64.0f), &s, &c);
      bool sinSlot = k>=128;
      float v;
      if (m<24) v = sinSlot? s : c;
      else      v = sinSlot? c : -s;
      u16 hh, ll; split2(v, hh, ll);
      E2h[i]=hh; E2l[i]=ll;
    }
  } else if (bid == 15){
    for (int i=t;i<8192;i+=256){
      int h=i>>6, k=i&63;
      float v=0.f;
      if (k<48){
        int kyi = (k<24)? k : k-24;
        int ky  = (kyi<12)? kyi : kyi+104;
        int mm  = (ky*h)&127;
        float s,c; sincospif((float)mm*(1.0f/64.0f), &s, &c);
        v = ((k<24)? c : s) * (1.0f/16384.0f);
      }
      u16 hh, ll; split2(v, hh, ll);
      E3h[i]=hh; E3l[i]=ll;
    }
  } else if (bid == 16){
    // Wc: 6 layers x [32 o][32 c] hi/lo; bsum[l][o] = wb+bb+cb
    for (int i=t;i<6144;i+=256){
      float v = wW[i];
      u16 hh, ll; split2(v, hh, ll);
      Wch[i]=hh; Wcl[i]=ll;
    }
    if (t < 192) bsum[t] = wb[t] + bb[t] + cb[t];
  } else {
    // E4 [128 w][32 k]: k=0 ->1; k=1 ->0; k=2kx -> 2cos(pi kx w/64);
    // k=2kx+1 -> -2 sin; k>=24 -> 0
    for (int i=t;i<4096;i+=256){
      int w=i>>5, k=i&31;
      float v=0.f;
      if (k < 24){
        int kx = k>>1, ri = k&1;
        if (kx==0) v = ri? 0.f : 1.f;
        else {
          float s,c; sincospif((float)(kx*w)*(1.0f/64.0f), &s, &c);
          v = ri? -2.f*s : 2.f*c;
        }
      }
      u16 hh, ll; split2(v, hh, ll);
      E4h[i]=hh; E4l[i]=ll;
    }
  }
}

// ------- H-DFT via MFMA: F1[bc][h][24] -> F2[b][kyi][col][32 c] -------------
__global__ __launch_bounds__(256) void k_dfth(const float* __restrict__ F1,
                      const u16* __restrict__ E2h, const u16* __restrict__ E2l,
                      float* __restrict__ F2){
  __shared__ u16 Fth[16*264], Ftl[16*264];
  int t=threadIdx.x;
  int bc = blockIdx.x;                            // 256 blocks
  int b = bc>>5, c = bc&31;
  const float* src = F1 + (size_t)bc*3072;
  for (int i=t;i<3072;i+=256){
    int h = i/24, col = i - h*24;
    int kx = col>>1, ri = col&1;
    u16 hh, ll; split2(src[i], hh, ll);
    int idx = kx*264 + ri*128 + h;
    Fth[idx] = hh; Ftl[idx] = ll;
  }
  __syncthreads();
  int wv = t>>6, lane = t&63, lr = lane&15, lg = lane>>4;
  if (wv < 3){
    f32x4 acc = (f32x4){0.f,0.f,0.f,0.f};
    #pragma unroll
    for (int ks=0; ks<8; ++ks){
      short8v af = *reinterpret_cast<const short8v*>(E2h + (size_t)(wv*16+lr)*256 + ks*32 + lg*8);
      short8v ag = *reinterpret_cast<const short8v*>(E2l + (size_t)(wv*16+lr)*256 + ks*32 + lg*8);
      short8v bf = *reinterpret_cast<const short8v*>(&Fth[lr*264 + ks*32 + lg*8]);
      short8v bg = *reinterpret_cast<const short8v*>(&Ftl[lr*264 + ks*32 + lg*8]);
      acc = __builtin_amdgcn_mfma_f32_16x16x32_bf16(af, bf, acc, 0,0,0);
      acc = __builtin_amdgcn_mfma_f32_16x16x32_bf16(af, bg, acc, 0,0,0);
      acc = __builtin_amdgcn_mfma_f32_16x16x32_bf16(ag, bf, acc, 0,0,0);
    }
    if (lr < 12){
      #pragma unroll
      for (int r=0;r<4;r++){
        int m = wv*16 + 4*lg + r;
        int kyi = (m<24)? m : m-24;
        int ri  = (m<24)? 0 : 1;
        F2[(((size_t)b*24 + kyi)*24 + 2*lr + ri)*32 + c] = acc[r];
      }
    }
  }
}

// ------- fused mode-mix + MFMA inverse H-DFT: F2 x wT2 -> S1 hi/lo ----------
__global__ __launch_bounds__(576) void k_mixid(const float* __restrict__ F2, const float* __restrict__ wTl,
                      const u16* __restrict__ E3h, const u16* __restrict__ E3l,
                      u16* __restrict__ S1h, u16* __restrict__ S1l){
  __shared__ u16 Bh[32*72], Bl[32*72];
  int t=threadIdx.x;
  int bo = blockIdx.x;            // 256 = b*32+o
  int b = bo>>5, o = bo&31;
  for (int i=t; i<24*24; i+=576){
    int row = i/24, k = 48 + i - (i/24)*24;
    Bh[row*72 + k] = 0; Bl[row*72 + k] = 0;
  }
  {
    int pair = t>>1, half = t&1;  // pair < 288
    int kx = pair%12, kyi = pair/12;
    int hf = kyi<12?0:1, kym = kyi<12?kyi:kyi-12;
    const float* fpr = F2 + (((size_t)b*24 + kyi)*24 + 2*kx)*32 + half*16;
    const float* fpi = fpr + 32;
    const float* wp = wTl + (size_t)(hf*12+kym)*24576 + kx*2048 + o*64 + half*32;
    float gr=0.f, gi=0.f;
    #pragma unroll 8
    for (int i=0;i<16;i++){
      float2 wv = *reinterpret_cast<const float2*>(wp + 2*i);
      float ar = fpr[i], ai = fpi[i];
      gr += ar*wv.x - ai*wv.y;
      gi += ar*wv.y + ai*wv.x;
    }
    gr += __shfl_xor(gr,1);
    gi += __shfl_xor(gi,1);
    if (half==0){
      u16 grh, grl, gih, gil, nih, nil;
      split2(gr, grh, grl);
      split2(gi, gih, gil);
      split2(-gi, nih, nil);
      int r0 = (2*kx)*72, r1 = (2*kx+1)*72;
      Bh[r0 + kyi]      = grh; Bl[r0 + kyi]      = grl;
      Bh[r0 + 24 + kyi] = nih; Bl[r0 + 24 + kyi] = nil;
      Bh[r1 + kyi]      = gih; Bl[r1 + kyi]      = gil;
      Bh[r1 + 24 + kyi] = grh; Bl[r1 + 24 + kyi] = grl;
    }
  }
  __syncthreads();
  int wv = t>>6, lane = t&63, lr = lane&15, lg = lane>>4;
  if (wv < 8){
    f32x4 acc[2];
    acc[0] = (f32x4){0.f,0.f,0.f,0.f};
    acc[1] = (f32x4){0.f,0.f,0.f,0.f};
    #pragma unroll
    for (int ks=0; ks<2; ++ks){
      short8v af = *reinterpret_cast<const short8v*>(E3h + (size_t)(wv*16+lr)*64 + ks*32 + lg*8);
      short8v ag = *reinterpret_cast<const short8v*>(E3l + (size_t)(wv*16+lr)*64 + ks*32 + lg*8);
      #pragma unroll
      for (int nt=0; nt<2; ++nt){
        short8v bf = *reinterpret_cast<const short8v*>(&Bh[(nt*16+lr)*72 + ks*32 + lg*8]);
        short8v bg = *reinterpret_cast<const short8v*>(&Bl[(nt*16+lr)*72 + ks*32 + lg*8]);
        acc[nt] = __builtin_amdgcn_mfma_f32_16x16x32_bf16(af, bf, acc[nt], 0,0,0);
        acc[nt] = __builtin_amdgcn_mfma_f32_16x16x32_bf16(af, bg, acc[nt], 0,0,0);
        acc[nt] = __builtin_amdgcn_mfma_f32_16x16x32_bf16(ag, bf, acc[nt], 0,0,0);
      }
    }
    #pragma unroll
    for (int nt=0; nt<2; ++nt){
      int n = nt*16 + lr;
      if (n < 24){
        #pragma unroll
        for (int r=0;r<4;r++){
          int h = wv*16 + 4*lg + r;
          size_t off = (size_t)bo*3072 + h*24 + n;
          u16 hh, ll; split2(acc[nt][r], hh, ll);
          S1h[off] = hh; S1l[off] = ll;
        }
      }
    }
  }
}

// --------- combine3 (256 threads): conv1x1 + spec iW-DFT via MFMA + bias
//           + GELU -> Yb hi/lo out; non-LAST also MFMA W-DFT -> F1.
template<int LAST>
__global__ __launch_bounds__(256) void k_combine3(
    const u16* __restrict__ Ybh_in, const u16* __restrict__ Ybl_in,
    const u16* __restrict__ S1h, const u16* __restrict__ S1l,
    const float* __restrict__ x,
    const u16* __restrict__ Wch, const u16* __restrict__ Wcl,   // + l*1024
    const u16* __restrict__ E4h, const u16* __restrict__ E4l,
    const float* __restrict__ bsuml,                            // + l*32
    const float* __restrict__ bWl, const float* __restrict__ cWl,
    const u16* __restrict__ Emh, const u16* __restrict__ Eml,
    float* __restrict__ F1,
    u16* __restrict__ Ybh_out, u16* __restrict__ Ybl_out){
  __shared__ u16 ybsp[2][32][136];
  __shared__ float bs[32], bwS[64], cwS[96];
  int t=threadIdx.x;
  int b = blockIdx.x>>7, h = blockIdx.x&127;
  if (t<32) bs[t]=bsuml[t];
  else if (t>=64 && t<128) bwS[t-64]=bWl[t-64];
  else if (t>=128 && t<224) cwS[t-128]=cWl[t-128];
  __syncthreads();
  int wv=t>>6, lane=t&63, lr=lane&15, lg=lane>>4;
  f32x4 acc[2][2];
  #pragma unroll
  for (int ot=0;ot<2;++ot){ acc[ot][0]=(f32x4){0,0,0,0}; acc[ot][1]=(f32x4){0,0,0,0}; }
  // conv1x1: A=Wc[o][c] hi/lo, B=y[w][c] hi/lo (direct from global)
  #pragma unroll
  for (int ot=0; ot<2; ++ot){
    int o = ot*16+lr;
    short8v af = *reinterpret_cast<const short8v*>(Wch + o*32 + lg*8);
    short8v al = *reinterpret_cast<const short8v*>(Wcl + o*32 + lg*8);
    #pragma unroll
    for (int j=0;j<2;++j){
      int w = (2*wv+j)*16 + lr;
      size_t yoff = (((size_t)(b*128+h))*128 + w)*32 + lg*8;
      short8v bh = *reinterpret_cast<const short8v*>(Ybh_in + yoff);
      short8v bl = *reinterpret_cast<const short8v*>(Ybl_in + yoff);
      acc[ot][j] = __builtin_amdgcn_mfma_f32_16x16x32_bf16(af, bh, acc[ot][j], 0,0,0);
      acc[ot][j] = __builtin_amdgcn_mfma_f32_16x16x32_bf16(af, bl, acc[ot][j], 0,0,0);
      acc[ot][j] = __builtin_amdgcn_mfma_f32_16x16x32_bf16(al, bh, acc[ot][j], 0,0,0);
    }
  }
  // spec: A=S1[o][k<24 pad32] hi/lo, B=E4[w][k] hi/lo
  #pragma unroll
  for (int ot=0; ot<2; ++ot){
    int o = ot*16+lr;
    size_t soff = (((size_t)(b*32+o))*128 + h)*24 + lg*8;
    short8v ah = *reinterpret_cast<const short8v*>(S1h + soff);
    short8v al2 = *reinterpret_cast<const short8v*>(S1l + soff);
    #pragma unroll
    for (int j=0;j<2;++j){
      int w = (2*wv+j)*16 + lr;
      short8v eh = *reinterpret_cast<const short8v*>(E4h + w*32 + lg*8);
      short8v el = *reinterpret_cast<const short8v*>(E4l + w*32 + lg*8);
      acc[ot][j] = __builtin_amdgcn_mfma_f32_16x16x32_bf16(ah, eh, acc[ot][j], 0,0,0);
      acc[ot][j] = __builtin_amdgcn_mfma_f32_16x16x32_bf16(al2, eh, acc[ot][j], 0,0,0);
      acc[ot][j] = __builtin_amdgcn_mfma_f32_16x16x32_bf16(ah, el, acc[ot][j], 0,0,0);
    }
  }
  // bias + gelu + emit (D: row o = ot*16+4lg+r, col w = (2wv+j)*16+lr)
  float gx = h*(1.0f/127.0f);
  #pragma unroll
  for (int j=0;j<2;++j){
    int w = (2*wv+j)*16 + lr;
    float4 xm = *reinterpret_cast<const float4*>(x + (((size_t)(b*128+h))*128+w)*4);
    float gy = w*(1.0f/127.0f);
    #pragma unroll
    for (int ot=0;ot<2;++ot){
      ushort4v hv, lvv;
      #pragma unroll
      for (int r=0;r<4;++r){
        int o = ot*16 + 4*lg + r;
        float v = acc[ot][j][r] + bs[o] + gx*bwS[2*o] + gy*bwS[2*o+1]
                + xm.y*cwS[3*o] + xm.z*cwS[3*o+1] + xm.w*cwS[3*o+2];
        float g = gelu_f(v);
        u16 hh, ll; split2(g, hh, ll);
        hv[r]=hh; lvv[r]=ll;
        if constexpr(!LAST){ ybsp[0][o][w]=hh; ybsp[1][o][w]=ll; }
      }
      size_t base = (((size_t)(b*128+h))*128 + w)*32 + ot*16 + 4*lg;
      *reinterpret_cast<ushort4v*>(Ybh_out + base) = hv;
      *reinterpret_cast<ushort4v*>(Ybl_out + base) = lvv;
    }
  }
  if constexpr(!LAST){
    __syncthreads();
    // forward W-DFT via MFMA: F1[o][m] = sum_w y[o][w]*Em[m][w] (bf16x3)
    int mt = wv&1, oj = wv>>1;
    f32x4 accm = (f32x4){0.f,0.f,0.f,0.f};
    #pragma unroll
    for (int ks=0; ks<4; ++ks){
      short8v ef = *reinterpret_cast<const short8v*>(Emh + (size_t)(mt*16+lr)*128 + ks*32 + lg*8);
      short8v eg = *reinterpret_cast<const short8v*>(Eml + (size_t)(mt*16+lr)*128 + ks*32 + lg*8);
      short8v yf = *reinterpret_cast<const short8v*>(&ybsp[0][oj*16+lr][ks*32+lg*8]);
      short8v yg = *reinterpret_cast<const short8v*>(&ybsp[1][oj*16+lr][ks*32+lg*8]);
      accm = __builtin_amdgcn_mfma_f32_16x16x32_bf16(ef, yf, accm, 0,0,0);
      accm = __builtin_amdgcn_mfma_f32_16x16x32_bf16(ef, yg, accm, 0,0,0);
      accm = __builtin_amdgcn_mfma_f32_16x16x32_bf16(eg, yf, accm, 0,0,0);
    }
    if (mt==0 || lg<2){
      int m = mt*16 + 4*lg;
      int o = oj*16 + lr;
      float4 v; v.x=accm[0]; v.y=accm[1]; v.z=accm[2]; v.w=accm[3];
      *reinterpret_cast<float4*>(&F1[((size_t)(b*32+o)*128 + h)*24 + m]) = v;
    }
  }
}

// ---- fused head: fc1 hoisted + single-barrier handoff; fc3/fc4/fc5 ---------
__global__ __launch_bounds__(256) void k_headm(
    const u16* __restrict__ Yb,                                 // [pix][32] bf16 hi
    const u16* __restrict__ W1h, const u16* __restrict__ W1l,
    const float* __restrict__ b1,
    const u16* __restrict__ W3h, const u16* __restrict__ W3l,
    const float* __restrict__ b3,
    const u16* __restrict__ W4h, const u16* __restrict__ W4l,
    const float* __restrict__ c45, const float* __restrict__ w5,
    float* __restrict__ out){
  __shared__ u16 Ac[64*264];
  __shared__ float b1s[256];
  __shared__ float b3s[128], w5s[128];
  __shared__ float part2[2][64];
  int t = threadIdx.x;
  int wv = t>>6, lane = t&63, lr = lane&15, lg = lane>>4;
  int P0 = blockIdx.x*64;
  b1s[t] = b1[t];
  if (t<128){ b3s[t]=b3[t]; w5s[t]=w5[t]; }
  int wn3 = wv>>1, wp = wv&1;
  short8v yb;
  {
    size_t p = (size_t)P0 + wv*16 + lr;
    yb = *reinterpret_cast<const short8v*>(Yb + p*32 + lg*8);
  }
  __syncthreads();
  unsigned q[8][2][2];
  #pragma unroll
  for (int kt=0; kt<8; ++kt){
    f32x4 a1[2];
    a1[0]=(f32x4){0,0,0,0}; a1[1]=(f32x4){0,0,0,0};
    #pragma unroll
    for (int i=0;i<2;i++){
      int n1 = kt*32 + i*16 + lr;
      short8v w1f = *reinterpret_cast<const short8v*>(W1h + (size_t)n1*32 + lg*8);
      short8v w1g = *reinterpret_cast<const short8v*>(W1l + (size_t)n1*32 + lg*8);
      a1[i] = __builtin_amdgcn_mfma_f32_16x16x32_bf16(w1f, yb, a1[i], 0,0,0);
      a1[i] = __builtin_amdgcn_mfma_f32_16x16x32_bf16(w1g, yb, a1[i], 0,0,0);
    }
    #pragma unroll
    for (int i=0;i<2;i++){
      int n1b = kt*32 + i*16 + 4*lg;
      u16 v0 = f2bf(gelu_f(a1[i][0] + b1s[n1b+0]));
      u16 v1 = f2bf(gelu_f(a1[i][1] + b1s[n1b+1]));
      u16 v2 = f2bf(gelu_f(a1[i][2] + b1s[n1b+2]));
      u16 v3 = f2bf(gelu_f(a1[i][3] + b1s[n1b+3]));
      q[kt][i][0] = (unsigned)v0 | ((unsigned)v1<<16);
      q[kt][i][1] = (unsigned)v2 | ((unsigned)v3<<16);
    }
  }
  {
    int p = wv*16 + lr;
    #pragma unroll
    for (int kt=0; kt<8; ++kt){
      #pragma unroll
      for (int i=0;i<2;i++){
        union { unsigned u[2]; ushort4v s; } cv;
        cv.u[0] = q[kt][i][0]; cv.u[1] = q[kt][i][1];
        *reinterpret_cast<ushort4v*>(&Ac[p*264 + kt*32 + i*16 + 4*lg]) = cv.s;
      }
    }
  }
  __syncthreads();
  f32x4 acc3[4][2];
  #pragma unroll
  for (int i=0;i<4;i++){ acc3[i][0]=(f32x4){0,0,0,0}; acc3[i][1]=(f32x4){0,0,0,0}; }
  #pragma unroll
  for (int kt=0; kt<8; ++kt){
    short8v ab[2];
    #pragma unroll
    for (int j=0;j<2;j++){
      int pb = wp*32 + j*16 + lr;
      ab[j] = *reinterpret_cast<const short8v*>(&Ac[pb*264 + kt*32 + lg*8]);
    }
    #pragma unroll
    for (int i=0;i<4;i++){
      int n3 = wn3*64 + i*16 + lr;
      short8v w3f = *reinterpret_cast<const short8v*>(W3h + (size_t)kt*4096 + n3*32 + lg*8);
      short8v w3g = *reinterpret_cast<const short8v*>(W3l + (size_t)kt*4096 + n3*32 + lg*8);
      #pragma unroll
      for (int j=0;j<2;j++){
        acc3[i][j] = __builtin_amdgcn_mfma_f32_16x16x32_bf16(w3f, ab[j], acc3[i][j], 0,0,0);
        acc3[i][j] = __builtin_amdgcn_mfma_f32_16x16x32_bf16(w3g, ab[j], acc3[i][j], 0,0,0);
      }
    }
  }
  __syncthreads();
  u16* A2 = Ac;
  #pragma unroll
  for (int i=0;i<4;i++){
    int n3b = wn3*64 + i*16 + 4*lg;
    #pragma unroll
    for (int j=0;j<2;j++){
      int p = wp*32 + j*16 + lr;
      ushort4v hv;
      #pragma unroll
      for (int r=0;r<4;r++){
        hv[r] = f2bf(gelu_f(acc3[i][j][r] + b3s[n3b+r]));
      }
      *reinterpret_cast<ushort4v*>(&A2[p*136 + n3b]) = hv;
    }
  }
  __syncthreads();
  f32x4 acc4[4][2];
  #pragma unroll
  for (int i=0;i<4;i++){ acc4[i][0]=(f32x4){0,0,0,0}; acc4[i][1]=(f32x4){0,0,0,0}; }
  #pragma unroll
  for (int ks=0; ks<4; ++ks){
    short8v p2[2];
    #pragma unroll
    for (int j=0;j<2;j++){
      int p = wp*32 + j*16 + lr;
      p2[j] = *reinterpret_cast<const short8v*>(&A2[p*136 + ks*32 + lg*8]);
    }
    #pragma unroll
    for (int i2=0;i2<4;i2++){
      int n4 = wn3*64 + i2*16 + lr;
      short8v w4f = *reinterpret_cast<const short8v*>(W4h + (size_t)ks*4096 + n4*32 + lg*8);
      short8v w4g = *reinterpret_cast<const short8v*>(W4l + (size_t)ks*4096 + n4*32 + lg*8);
      #pragma unroll
      for (int j=0;j<2;j++){
        acc4[i2][j] = __builtin_amdgcn_mfma_f32_16x16x32_bf16(w4f, p2[j], acc4[i2][j], 0,0,0);
        acc4[i2][j] = __builtin_amdgcn_mfma_f32_16x16x32_bf16(w4g, p2[j], acc4[i2][j], 0,0,0);
      }
    }
  }
  #pragma unroll
  for (int j=0;j<2;j++){
    float part = 0.f;
    #pragma unroll
    for (int i2=0;i2<4;i2++){
      #pragma unroll
      for (int r=0;r<4;r++){
        int n4 = wn3*64 + i2*16 + 4*lg + r;
        part += acc4[i2][j][r] * w5s[n4];
      }
    }
    part += __shfl_xor(part, 16); part += __shfl_xor(part, 32);
    if (lg==0) part2[wn3][wp*32 + j*16 + lr] = part;
  }
  __syncthreads();
  if (t<64) out[P0 + t] = part2[0][t] + part2[1][t] + c45[0];
}

extern "C" void kernel_launch(void* const* d_in, const int* in_sizes, int n_in,
                              void* d_out, int out_size, void* d_ws, size_t ws_size,
                              hipStream_t stream){
  const float* x     = (const float*)d_in[0];
  const float* fc0_W = (const float*)d_in[1];
  const float* fc0_b = (const float*)d_in[2];
  const float* spec_w= (const float*)d_in[3];
  const float* wW    = (const float*)d_in[4];
  const float* wb    = (const float*)d_in[5];
  const float* bW    = (const float*)d_in[6];
  const float* bb    = (const float*)d_in[7];
  const float* cW    = (const float*)d_in[8];
  const float* cb    = (const float*)d_in[9];
  const float* fc1_W = (const float*)d_in[10];
  const float* fc1_b = (const float*)d_in[11];
  const float* fc3_W = (const float*)d_in[12];
  const float* fc3_b = (const float*)d_in[13];
  const float* fc4_W = (const float*)d_in[14];
  const float* fc4_b = (const float*)d_in[15];
  const float* fc5_W = (const float*)d_in[16];
  const float* fc5_b = (const float*)d_in[17];
  float* out = (float*)d_out;
  float* ws  = (float*)d_ws;

  // workspace map (floats unless noted)
  u16*   YbA  = (u16*)ws;                  // 8,388,608 u16
  u16*   YbB  = YbA + 8388608;             // 8,388,608 u16
  float* wT   = ws + 8388608;              // 3,538,944 f
  float* F2   = wT + 3538944;              //   147,456 f
  u16*   S1h  = (u16*)(F2 + 147456);       //   786,496 u16 (incl pad)
  u16*   S1l  = S1h + 786496;              //   786,496 u16
  float* F1   = (float*)(S1l + 786496);    //   786,432 f
  float* WP   = F1 + 786432;
  u16*   W1h = (u16*)WP;
  u16*   W1l = W1h + 8192;
  u16*   W3h = W1l + 8192;
  u16*   W3l = W3h + 32768;
  u16*   W4h = W3l + 32768;
  u16*   W4l = W4h + 16384;
  u16*   Emh = W4l + 16384;
  u16*   Eml = Emh + 4096;
  u16*   E2h = Eml + 4096;
  u16*   E2l = E2h + 12288;
  u16*   E3h = E2l + 12288;
  u16*   E3l = E3h + 8192;
  u16*   Wch = E3l + 8192;                 // 6,144 u16
  u16*   Wcl = Wch + 6144;
  u16*   E4h = Wcl + 6144;                 // 4,096 u16
  u16*   E4l = E4h + 4096;
  float* bsum = (float*)(E4l + 4096);      // 192 f
  float* c45  = bsum + 192;
  u16*   YbhA = YbA;
  u16*   YblA = YbA + 4194304;
  u16*   YbhB = YbB;
  u16*   YblB = YbB + 4194304;

  k_fc0f<<<512,256,0,stream>>>(x, fc0_W, fc0_b, YbhA, YblA, F1);
  k_wtrans<<<288,256,0,stream>>>(spec_w, wT);
  k_wprep<<<18,256,0,stream>>>(fc1_W, fc3_W, fc4_W, fc4_b, fc5_W, fc5_b,
                               wW, wb, bb, cb,
                               W1h, W1l, W3h, W3l, W4h, W4l, Emh, Eml,
                               E2h, E2l, E3h, E3l, Wch, Wcl, E4h, E4l,
                               bsum, c45);

  for (int l=0;l<NL;l++){
    const u16* Yih = (l&1)? YbhB : YbhA;
    const u16* Yil = (l&1)? YblB : YblA;
    u16* Yoh = (l&1)? YbhA : YbhB;
    u16* Yol = (l&1)? YblA : YblB;
    k_dfth<<<256,256,0,stream>>>(F1, E2h, E2l, F2);
    k_mixid<<<256,576,0,stream>>>(F2, wT + (size_t)l*589824, E3h, E3l, S1h, S1l);
    if (l < NL-1){
      k_combine3<0><<<1024,256,0,stream>>>(Yih, Yil, S1h, S1l, x,
                                     Wch + l*1024, Wcl + l*1024, E4h, E4l,
                                     bsum + l*32, bW + (size_t)l*64, cW + (size_t)l*96,
                                     Emh, Eml, F1, Yoh, Yol);
    } else {
      k_combine3<1><<<1024,256,0,stream>>>(Yih, Yil, S1h, S1l, x,
                                     Wch + l*1024, Wcl + l*1024, E4h, E4l,
                                     bsum + l*32, bW + (size_t)l*64, cW + (size_t)l*96,
                                     Emh, Eml, nullptr, Yoh, Yol);
    }
  }

  // NL=6 even: final combine (l=5) reads B, writes A -> head reads YbhA
  k_headm<<<2048,256,0,stream>>>(YbhA, W1h, W1l, fc1_b, W3h, W3l, fc3_b,
                                 W4h, W4l, c45, fc5_W, out);
}